// Round 1
// baseline (637.671 us; speedup 1.0000x reference)
//
#include <hip/hip_runtime.h>

#define N_NODES 50000
#define N_EDGES 800000
#define N_FEAT 128
#define HIDDEN 64
#define N_CLASSES 16

// deg[i] = 1.0 (self-loop contribution)
__global__ void k_init_deg(float* __restrict__ deg) {
    int i = blockIdx.x * 256 + threadIdx.x;
    if (i < N_NODES) deg[i] = 1.0f;
}

// deg[dst] += 1 for every edge
__global__ void k_deg_accum(const int* __restrict__ ei, float* __restrict__ deg) {
    int e = blockIdx.x * 256 + threadIdx.x;
    if (e < N_EDGES) unsafeAtomicAdd(&deg[ei[N_EDGES + e]], 1.0f);
}

// deg -> deg^-1/2 in place (deg >= 1 always, so no zero guard needed)
__global__ void k_dinv(float* __restrict__ deg) {
    int i = blockIdx.x * 256 + threadIdx.x;
    if (i < N_NODES) deg[i] = rsqrtf(deg[i]);
}

// out[node, f] = sum_k a[node, k] * w[k, f]   (w staged in LDS)
// block = 256 threads = 4 nodes x 64 features; grid = N_NODES/4 (exact)
template <int K>
__global__ void k_mm(const float* __restrict__ a, const float* __restrict__ w,
                     float* __restrict__ out) {
    __shared__ float Ws[K * HIDDEN];
    int tid = threadIdx.x;
    for (int i = tid; i < K * HIDDEN; i += 256) Ws[i] = w[i];
    __syncthreads();
    int node = blockIdx.x * 4 + (tid >> 6);   // wave-uniform
    int f = tid & 63;
    const float* ar = a + (long)node * K;
    float acc = 0.0f;
#pragma unroll
    for (int k = 0; k < K; ++k) acc = fmaf(ar[k], Ws[k * HIDDEN + f], acc);
    out[(long)node * HIDDEN + f] = acc;
}

__global__ void k_zero(float* __restrict__ buf) {
    int i = blockIdx.x * 256 + threadIdx.x;
    if (i < N_NODES * HIDDEN) buf[i] = 0.0f;
}

// one wave per edge: lane l handles feature l
// agg[dst, f] += h[src, f] * dinv[src] * dinv[dst]
__global__ void k_scatter(const float* __restrict__ h, const int* __restrict__ ei,
                          const float* __restrict__ dinv, float* __restrict__ agg) {
    int t = blockIdx.x * 256 + threadIdx.x;
    int e = t >> 6;                            // wave-uniform
    if (e >= N_EDGES) return;
    int f = t & 63;
    int s = ei[e];
    int d = ei[N_EDGES + e];
    float nrm = dinv[s] * dinv[d];
    unsafeAtomicAdd(&agg[(long)d * HIDDEN + f], h[(long)s * HIDDEN + f] * nrm);
}

// agg = relu(agg + h * dinv^2 + bias)   (self-loop term folded in here)
__global__ void k_fuse(float* __restrict__ agg, const float* __restrict__ h,
                       const float* __restrict__ dinv, const float* __restrict__ bias) {
    int t = blockIdx.x * 256 + threadIdx.x;
    if (t >= N_NODES * HIDDEN) return;
    int node = t >> 6;
    int f = t & 63;
    float di = dinv[node];
    float v = agg[t] + h[t] * di * di + bias[f];
    agg[t] = fmaxf(v, 0.0f);
}

// logits = h @ Wout + bout, then softmax over 16 classes.
// 16 lanes per node (lane = class); shuffle-reduce max/sum within groups of 16.
__global__ void k_out(const float* __restrict__ h, const float* __restrict__ w,
                      const float* __restrict__ b, float* __restrict__ out) {
    __shared__ float Ws[HIDDEN * N_CLASSES];
    __shared__ float bs[N_CLASSES];
    int tid = threadIdx.x;
    for (int i = tid; i < HIDDEN * N_CLASSES; i += 256) Ws[i] = w[i];
    if (tid < N_CLASSES) bs[tid] = b[tid];
    __syncthreads();
    int node = blockIdx.x * 16 + (tid >> 4);
    int c = tid & 15;
    const float* hr = h + (long)node * HIDDEN;
    float acc = bs[c];
#pragma unroll
    for (int k = 0; k < HIDDEN; ++k) acc = fmaf(hr[k], Ws[k * N_CLASSES + c], acc);
    float m = acc;
#pragma unroll
    for (int off = 8; off; off >>= 1) m = fmaxf(m, __shfl_xor(m, off, 16));
    float ex = expf(acc - m);
    float s = ex;
#pragma unroll
    for (int off = 8; off; off >>= 1) s += __shfl_xor(s, off, 16);
    out[(long)node * N_CLASSES + c] = ex / s;
}

extern "C" void kernel_launch(void* const* d_in, const int* in_sizes, int n_in,
                              void* d_out, int out_size, void* d_ws, size_t ws_size,
                              hipStream_t stream) {
    const float* x    = (const float*)d_in[0];
    const int*   ei   = (const int*)d_in[1];   // [2, E] row-major: src row then dst row
    const float* W1   = (const float*)d_in[2];
    const float* b1   = (const float*)d_in[3];
    const float* W2   = (const float*)d_in[4];
    const float* b2   = (const float*)d_in[5];
    const float* Wout = (const float*)d_in[6];
    const float* bout = (const float*)d_in[7];
    float* out = (float*)d_out;

    char* ws = (char*)d_ws;
    float* dinv = (float*)ws;                                     // 50000 f32
    float* bufA = (float*)(ws + ((N_NODES * 4 + 255) / 256) * 256);  // 12.8 MB
    float* bufB = bufA + (size_t)N_NODES * HIDDEN;                   // 12.8 MB

    const int NB_NODE = (N_NODES + 255) / 256;
    const int NB_EDGE = (N_EDGES + 255) / 256;
    const int NB_FEATMAT = (N_NODES * HIDDEN + 255) / 256;  // 12500
    const int NB_SCAT = (N_EDGES * 64) / 256;               // 200000

    // ---- normalization coefficients ----
    k_init_deg<<<NB_NODE, 256, 0, stream>>>(dinv);
    k_deg_accum<<<NB_EDGE, 256, 0, stream>>>(ei, dinv);
    k_dinv<<<NB_NODE, 256, 0, stream>>>(dinv);

    // ---- layer 1: H1 = X @ W1 ; A1 = scatter(H1) ; H1a = relu(A1 + H1*dinv^2 + b1) ----
    k_mm<N_FEAT><<<N_NODES / 4, 256, 0, stream>>>(x, W1, bufA);
    k_zero<<<NB_FEATMAT, 256, 0, stream>>>(bufB);
    k_scatter<<<NB_SCAT, 256, 0, stream>>>(bufA, ei, dinv, bufB);
    k_fuse<<<NB_FEATMAT, 256, 0, stream>>>(bufB, bufA, dinv, b1);

    // ---- layer 2: H2 = H1a @ W2 ; A2 = scatter(H2) ; H2a = relu(A2 + H2*dinv^2 + b2) ----
    k_mm<HIDDEN><<<N_NODES / 4, 256, 0, stream>>>(bufB, W2, bufA);
    k_zero<<<NB_FEATMAT, 256, 0, stream>>>(bufB);
    k_scatter<<<NB_SCAT, 256, 0, stream>>>(bufA, ei, dinv, bufB);
    k_fuse<<<NB_FEATMAT, 256, 0, stream>>>(bufB, bufA, dinv, b2);

    // ---- output layer + softmax ----
    k_out<<<N_NODES / 16, 256, 0, stream>>>(bufB, Wout, bout, out);
}

// Round 2
// 413.351 us; speedup vs baseline: 1.5427x; 1.5427x over previous
//
#include <hip/hip_runtime.h>

#define N_NODES 50000
#define N_EDGES 800000
#define N_FEAT 128
#define HIDDEN 64
#define N_CLASSES 16
#define NBLK_NODE 196  // ceil(50000/256)

// cnt[dst]++ for every edge (int atomics; deg = cnt + 1 self-loop)
__global__ void k_count(const int* __restrict__ ei, int* __restrict__ cnt) {
    int e = blockIdx.x * 256 + threadIdx.x;
    if (e < N_EDGES) atomicAdd(&cnt[ei[N_EDGES + e]], 1);
}

// per-256-chunk exclusive scan of cnt -> rs (local), chunk totals -> bsum
__global__ void k_scan1(const int* __restrict__ cnt, int* __restrict__ rs,
                        int* __restrict__ bsum) {
    __shared__ int sm[256];
    int tid = threadIdx.x;
    int i = blockIdx.x * 256 + tid;
    int v = (i < N_NODES) ? cnt[i] : 0;
    sm[tid] = v;
    __syncthreads();
#pragma unroll
    for (int off = 1; off < 256; off <<= 1) {
        int t = (tid >= off) ? sm[tid - off] : 0;
        __syncthreads();
        sm[tid] += t;
        __syncthreads();
    }
    if (i < N_NODES) rs[i] = sm[tid] - v;  // exclusive
    if (tid == 255) bsum[blockIdx.x] = sm[255];
}

// single-block exclusive scan of the 196 chunk totals -> boff
__global__ void k_scan2(const int* __restrict__ bsum, int* __restrict__ boff) {
    __shared__ int sm[256];
    int tid = threadIdx.x;
    int v = (tid < NBLK_NODE) ? bsum[tid] : 0;
    sm[tid] = v;
    __syncthreads();
#pragma unroll
    for (int off = 1; off < 256; off <<= 1) {
        int t = (tid >= off) ? sm[tid - off] : 0;
        __syncthreads();
        sm[tid] += t;
        __syncthreads();
    }
    boff[tid] = sm[tid] - v;  // exclusive
}

// finalize: rs global offsets, cursor copy, dinv = (deg)^-1/2, sentinel rs[N]=E
__global__ void k_scan3(const int* __restrict__ cnt, int* __restrict__ rs,
                        const int* __restrict__ boff, int* __restrict__ cursor,
                        float* __restrict__ dinv) {
    int i = blockIdx.x * 256 + threadIdx.x;
    if (i < N_NODES) {
        int r = rs[i] + boff[blockIdx.x];
        rs[i] = r;
        cursor[i] = r;
        dinv[i] = rsqrtf((float)cnt[i] + 1.0f);
    }
    if (i == 0) rs[N_NODES] = N_EDGES;
}

// scatter edges into CSR buckets: csr[p] = {src, norm}
__global__ void k_fill(const int* __restrict__ ei, const float* __restrict__ dinv,
                       int* __restrict__ cursor, int2* __restrict__ csr) {
    int e = blockIdx.x * 256 + threadIdx.x;
    if (e >= N_EDGES) return;
    int s = ei[e];
    int d = ei[N_EDGES + e];
    float nrm = dinv[s] * dinv[d];
    int p = atomicAdd(&cursor[d], 1);
    csr[p] = make_int2(s, __float_as_int(nrm));
}

// out[node,f] = sum_k a[node,k] * w[k,f]; W staged in LDS.
// wave handles 4 nodes (4 accumulators/thread), lane = feature.
// grid = N_NODES/16 (exact: 3125), block = 256 = 4 waves -> 16 nodes/block.
template <int K>
__global__ void k_mm(const float* __restrict__ a, const float* __restrict__ w,
                     float* __restrict__ out) {
    __shared__ float Ws[K * HIDDEN];
    int tid = threadIdx.x;
    for (int i = tid; i < K * HIDDEN; i += 256) Ws[i] = w[i];
    __syncthreads();
    int f = tid & 63;
    int wv = tid >> 6;
    long n0 = (long)blockIdx.x * 16 + wv * 4;  // wave-uniform
    const float* a0 = a + n0 * K;
    float acc0 = 0.f, acc1 = 0.f, acc2 = 0.f, acc3 = 0.f;
    for (int k = 0; k < K; k += 4) {
        float va[4], vb[4], vc[4], vd[4];
        *(float4*)va = *(const float4*)(a0 + k);
        *(float4*)vb = *(const float4*)(a0 + K + k);
        *(float4*)vc = *(const float4*)(a0 + 2 * K + k);
        *(float4*)vd = *(const float4*)(a0 + 3 * K + k);
#pragma unroll
        for (int kk = 0; kk < 4; ++kk) {
            float wk = Ws[(k + kk) * HIDDEN + f];
            acc0 = fmaf(va[kk], wk, acc0);
            acc1 = fmaf(vb[kk], wk, acc1);
            acc2 = fmaf(vc[kk], wk, acc2);
            acc3 = fmaf(vd[kk], wk, acc3);
        }
    }
    float* o = out + n0 * HIDDEN + f;
    o[0] = acc0;
    o[HIDDEN] = acc1;
    o[2 * HIDDEN] = acc2;
    o[3 * HIDDEN] = acc3;
}

// fused aggregation: out[d,f] = relu( sum_{e->d} h[src,f]*norm + h[d,f]*dinv[d]^2 + b[f] )
// one wave per node, lane = feature. grid = N_NODES/4 (exact: 12500).
__global__ void k_gather(const float* __restrict__ h, const int2* __restrict__ csr,
                         const int* __restrict__ rs, const float* __restrict__ dinv,
                         const float* __restrict__ bias, float* __restrict__ out) {
    int t = blockIdx.x * 256 + threadIdx.x;
    int node = t >> 6;  // wave-uniform
    int f = t & 63;
    int r0 = rs[node];
    int r1 = rs[node + 1];
    float di = dinv[node];
    float acc = h[(long)node * HIDDEN + f] * di * di;
    for (int j = r0; j < r1; ++j) {
        int2 sn = csr[j];  // wave-uniform address
        acc = fmaf(h[(long)sn.x * HIDDEN + f], __int_as_float(sn.y), acc);
    }
    out[(long)node * HIDDEN + f] = fmaxf(acc + bias[f], 0.0f);
}

// logits = h @ Wout + bout, softmax over 16 classes (16 lanes per node).
__global__ void k_out(const float* __restrict__ h, const float* __restrict__ w,
                      const float* __restrict__ b, float* __restrict__ out) {
    __shared__ float Ws[HIDDEN * N_CLASSES];
    __shared__ float bs[N_CLASSES];
    int tid = threadIdx.x;
    for (int i = tid; i < HIDDEN * N_CLASSES; i += 256) Ws[i] = w[i];
    if (tid < N_CLASSES) bs[tid] = b[tid];
    __syncthreads();
    int node = blockIdx.x * 16 + (tid >> 4);
    int c = tid & 15;
    const float* hr = h + (long)node * HIDDEN;
    float acc = bs[c];
#pragma unroll
    for (int k = 0; k < HIDDEN; ++k) acc = fmaf(hr[k], Ws[k * N_CLASSES + c], acc);
    float m = acc;
#pragma unroll
    for (int off = 8; off; off >>= 1) m = fmaxf(m, __shfl_xor(m, off, 16));
    float ex = expf(acc - m);
    float s = ex;
#pragma unroll
    for (int off = 8; off; off >>= 1) s += __shfl_xor(s, off, 16);
    out[(long)node * N_CLASSES + c] = ex / s;
}

extern "C" void kernel_launch(void* const* d_in, const int* in_sizes, int n_in,
                              void* d_out, int out_size, void* d_ws, size_t ws_size,
                              hipStream_t stream) {
    const float* x    = (const float*)d_in[0];
    const int*   ei   = (const int*)d_in[1];
    const float* W1   = (const float*)d_in[2];
    const float* b1   = (const float*)d_in[3];
    const float* W2   = (const float*)d_in[4];
    const float* b2   = (const float*)d_in[5];
    const float* Wout = (const float*)d_in[6];
    const float* bout = (const float*)d_in[7];
    float* out = (float*)d_out;

    char* ws = (char*)d_ws;
    const size_t SZ_NODE_I = 200192;  // 50000*4 rounded to 256
    int*   cnt    = (int*)ws;                          ws += SZ_NODE_I;
    int*   rs     = (int*)ws;                          ws += SZ_NODE_I + 256;  // 50001 ints
    int*   cursor = (int*)ws;                          ws += SZ_NODE_I;
    float* dinv   = (float*)ws;                        ws += SZ_NODE_I;
    int*   bsum   = (int*)ws;                          ws += 1024;
    int*   boff   = (int*)ws;                          ws += 1024;
    int2*  csr    = (int2*)ws;                         ws += (size_t)N_EDGES * 8;
    float* bufA   = (float*)ws;                        ws += (size_t)N_NODES * HIDDEN * 4;
    float* bufB   = (float*)ws;

    const int NB_EDGE = (N_EDGES + 255) / 256;

    // ---- CSR build + normalization ----
    hipMemsetAsync(cnt, 0, (size_t)N_NODES * 4, stream);
    k_count<<<NB_EDGE, 256, 0, stream>>>(ei, cnt);
    k_scan1<<<NBLK_NODE, 256, 0, stream>>>(cnt, rs, bsum);
    k_scan2<<<1, 256, 0, stream>>>(bsum, boff);
    k_scan3<<<NBLK_NODE, 256, 0, stream>>>(cnt, rs, boff, cursor, dinv);
    k_fill<<<NB_EDGE, 256, 0, stream>>>(ei, dinv, cursor, csr);

    // ---- layer 1 ----
    k_mm<N_FEAT><<<N_NODES / 16, 256, 0, stream>>>(x, W1, bufA);
    k_gather<<<N_NODES / 4, 256, 0, stream>>>(bufA, csr, rs, dinv, b1, bufB);

    // ---- layer 2 ----
    k_mm<HIDDEN><<<N_NODES / 16, 256, 0, stream>>>(bufB, W2, bufA);
    k_gather<<<N_NODES / 4, 256, 0, stream>>>(bufA, csr, rs, dinv, b2, bufB);

    // ---- output layer + softmax ----
    k_out<<<N_NODES / 16, 256, 0, stream>>>(bufB, Wout, bout, out);
}

// Round 3
// 326.016 us; speedup vs baseline: 1.9559x; 1.2679x over previous
//
#include <hip/hip_runtime.h>

#define N_NODES 50000
#define N_EDGES 800000
#define N_FEAT 128
#define HIDDEN 64
#define N_CLASSES 16
#define NBLK_NODE 196  // ceil(50000/256)

// cnt[dst]++ for every edge (int atomics; deg = cnt + 1 self-loop)
__global__ void k_count(const int* __restrict__ ei, int* __restrict__ cnt) {
    int e = blockIdx.x * 256 + threadIdx.x;
    if (e < N_EDGES) atomicAdd(&cnt[ei[N_EDGES + e]], 1);
}

// per-256-chunk exclusive scan of cnt -> rs (local), chunk totals -> bsum
__global__ void k_scan1(const int* __restrict__ cnt, int* __restrict__ rs,
                        int* __restrict__ bsum) {
    __shared__ int sm[256];
    int tid = threadIdx.x;
    int i = blockIdx.x * 256 + tid;
    int v = (i < N_NODES) ? cnt[i] : 0;
    sm[tid] = v;
    __syncthreads();
#pragma unroll
    for (int off = 1; off < 256; off <<= 1) {
        int t = (tid >= off) ? sm[tid - off] : 0;
        __syncthreads();
        sm[tid] += t;
        __syncthreads();
    }
    if (i < N_NODES) rs[i] = sm[tid] - v;  // exclusive
    if (tid == 255) bsum[blockIdx.x] = sm[255];
}

// single-block exclusive scan of the 196 chunk totals -> boff
__global__ void k_scan2(const int* __restrict__ bsum, int* __restrict__ boff) {
    __shared__ int sm[256];
    int tid = threadIdx.x;
    int v = (tid < NBLK_NODE) ? bsum[tid] : 0;
    sm[tid] = v;
    __syncthreads();
#pragma unroll
    for (int off = 1; off < 256; off <<= 1) {
        int t = (tid >= off) ? sm[tid - off] : 0;
        __syncthreads();
        sm[tid] += t;
        __syncthreads();
    }
    boff[tid] = sm[tid] - v;  // exclusive
}

// finalize: rs global offsets, cursor copy, dinv = (deg)^-1/2, sentinel rs[N]=E
__global__ void k_scan3(const int* __restrict__ cnt, int* __restrict__ rs,
                        const int* __restrict__ boff, int* __restrict__ cursor,
                        float* __restrict__ dinv) {
    int i = blockIdx.x * 256 + threadIdx.x;
    if (i < N_NODES) {
        int r = rs[i] + boff[blockIdx.x];
        rs[i] = r;
        cursor[i] = r;
        dinv[i] = rsqrtf((float)cnt[i] + 1.0f);
    }
    if (i == 0) rs[N_NODES] = N_EDGES;
}

// scatter edges into CSR buckets: csr[p] = {src, norm}
__global__ void k_fill(const int* __restrict__ ei, const float* __restrict__ dinv,
                       int* __restrict__ cursor, int2* __restrict__ csr) {
    int e = blockIdx.x * 256 + threadIdx.x;
    if (e >= N_EDGES) return;
    int s = ei[e];
    int d = ei[N_EDGES + e];
    float nrm = dinv[s] * dinv[d];
    int p = atomicAdd(&cursor[d], 1);
    csr[p] = make_int2(s, __float_as_int(nrm));
}

// out[node,f] = sum_k a[node,k] * w[k,f]; W staged in LDS.
// wave handles 4 nodes (4 accumulators/thread), lane = feature.
// grid = N_NODES/16 (exact: 3125), block = 256 = 4 waves -> 16 nodes/block.
template <int K>
__global__ void k_mm(const float* __restrict__ a, const float* __restrict__ w,
                     float* __restrict__ out) {
    __shared__ float Ws[K * HIDDEN];
    int tid = threadIdx.x;
    for (int i = tid; i < K * HIDDEN; i += 256) Ws[i] = w[i];
    __syncthreads();
    int f = tid & 63;
    int wv = tid >> 6;
    long n0 = (long)blockIdx.x * 16 + wv * 4;  // wave-uniform
    const float* a0 = a + n0 * K;
    float acc0 = 0.f, acc1 = 0.f, acc2 = 0.f, acc3 = 0.f;
    for (int k = 0; k < K; k += 4) {
        float va[4], vb[4], vc[4], vd[4];
        *(float4*)va = *(const float4*)(a0 + k);
        *(float4*)vb = *(const float4*)(a0 + K + k);
        *(float4*)vc = *(const float4*)(a0 + 2 * K + k);
        *(float4*)vd = *(const float4*)(a0 + 3 * K + k);
#pragma unroll
        for (int kk = 0; kk < 4; ++kk) {
            float wk = Ws[(k + kk) * HIDDEN + f];
            acc0 = fmaf(va[kk], wk, acc0);
            acc1 = fmaf(vb[kk], wk, acc1);
            acc2 = fmaf(vc[kk], wk, acc2);
            acc3 = fmaf(vd[kk], wk, acc3);
        }
    }
    float* o = out + n0 * HIDDEN + f;
    o[0] = acc0;
    o[HIDDEN] = acc1;
    o[2 * HIDDEN] = acc2;
    o[3 * HIDDEN] = acc3;
}

// fused aggregation: out[d,f] = relu( sum_{e->d} h[src,f]*norm + h[d,f]*dinv[d]^2 + b[f] )
// one wave per node, lane = feature. 8-edge batches: 8 independent csr loads,
// then 8 independent h-row loads in flight -> hides L2/L3 latency.
__global__ void k_gather(const float* __restrict__ h, const int2* __restrict__ csr,
                         const int* __restrict__ rs, const float* __restrict__ dinv,
                         const float* __restrict__ bias, float* __restrict__ out) {
    int t = blockIdx.x * 256 + threadIdx.x;
    int node = t >> 6;  // wave-uniform
    int f = t & 63;
    int r0 = rs[node];
    int r1 = rs[node + 1];
    float di = dinv[node];
    float acc = h[(long)node * HIDDEN + f] * di * di;

    int j = r0;
    while (j + 8 <= r1) {
        int2 e0 = csr[j + 0], e1 = csr[j + 1], e2 = csr[j + 2], e3 = csr[j + 3];
        int2 e4 = csr[j + 4], e5 = csr[j + 5], e6 = csr[j + 6], e7 = csr[j + 7];
        float v0 = h[(long)e0.x * HIDDEN + f];
        float v1 = h[(long)e1.x * HIDDEN + f];
        float v2 = h[(long)e2.x * HIDDEN + f];
        float v3 = h[(long)e3.x * HIDDEN + f];
        float v4 = h[(long)e4.x * HIDDEN + f];
        float v5 = h[(long)e5.x * HIDDEN + f];
        float v6 = h[(long)e6.x * HIDDEN + f];
        float v7 = h[(long)e7.x * HIDDEN + f];
        acc = fmaf(v0, __int_as_float(e0.y), acc);
        acc = fmaf(v1, __int_as_float(e1.y), acc);
        acc = fmaf(v2, __int_as_float(e2.y), acc);
        acc = fmaf(v3, __int_as_float(e3.y), acc);
        acc = fmaf(v4, __int_as_float(e4.y), acc);
        acc = fmaf(v5, __int_as_float(e5.y), acc);
        acc = fmaf(v6, __int_as_float(e6.y), acc);
        acc = fmaf(v7, __int_as_float(e7.y), acc);
        j += 8;
    }
    while (j + 2 <= r1) {
        int2 e0 = csr[j + 0], e1 = csr[j + 1];
        float v0 = h[(long)e0.x * HIDDEN + f];
        float v1 = h[(long)e1.x * HIDDEN + f];
        acc = fmaf(v0, __int_as_float(e0.y), acc);
        acc = fmaf(v1, __int_as_float(e1.y), acc);
        j += 2;
    }
    if (j < r1) {
        int2 e0 = csr[j];
        acc = fmaf(h[(long)e0.x * HIDDEN + f], __int_as_float(e0.y), acc);
    }
    out[(long)node * HIDDEN + f] = fmaxf(acc + bias[f], 0.0f);
}

// logits = h @ Wout + bout, softmax over 16 classes (16 lanes per node).
__global__ void k_out(const float* __restrict__ h, const float* __restrict__ w,
                      const float* __restrict__ b, float* __restrict__ out) {
    __shared__ float Ws[HIDDEN * N_CLASSES];
    __shared__ float bs[N_CLASSES];
    int tid = threadIdx.x;
    for (int i = tid; i < HIDDEN * N_CLASSES; i += 256) Ws[i] = w[i];
    if (tid < N_CLASSES) bs[tid] = b[tid];
    __syncthreads();
    int node = blockIdx.x * 16 + (tid >> 4);
    int c = tid & 15;
    const float* hr = h + (long)node * HIDDEN;
    float acc = bs[c];
#pragma unroll
    for (int k = 0; k < HIDDEN; ++k) acc = fmaf(hr[k], Ws[k * N_CLASSES + c], acc);
    float m = acc;
#pragma unroll
    for (int off = 8; off; off >>= 1) m = fmaxf(m, __shfl_xor(m, off, 16));
    float ex = expf(acc - m);
    float s = ex;
#pragma unroll
    for (int off = 8; off; off >>= 1) s += __shfl_xor(s, off, 16);
    out[(long)node * N_CLASSES + c] = ex / s;
}

extern "C" void kernel_launch(void* const* d_in, const int* in_sizes, int n_in,
                              void* d_out, int out_size, void* d_ws, size_t ws_size,
                              hipStream_t stream) {
    const float* x    = (const float*)d_in[0];
    const int*   ei   = (const int*)d_in[1];
    const float* W1   = (const float*)d_in[2];
    const float* b1   = (const float*)d_in[3];
    const float* W2   = (const float*)d_in[4];
    const float* b2   = (const float*)d_in[5];
    const float* Wout = (const float*)d_in[6];
    const float* bout = (const float*)d_in[7];
    float* out = (float*)d_out;

    char* ws = (char*)d_ws;
    const size_t SZ_NODE_I = 200192;  // 50000*4 rounded to 256
    int*   cnt    = (int*)ws;                          ws += SZ_NODE_I;
    int*   rs     = (int*)ws;                          ws += SZ_NODE_I + 256;  // 50001 ints
    int*   cursor = (int*)ws;                          ws += SZ_NODE_I;
    float* dinv   = (float*)ws;                        ws += SZ_NODE_I;
    int*   bsum   = (int*)ws;                          ws += 1024;
    int*   boff   = (int*)ws;                          ws += 1024;
    int2*  csr    = (int2*)ws;                         ws += (size_t)N_EDGES * 8;
    float* bufA   = (float*)ws;                        ws += (size_t)N_NODES * HIDDEN * 4;
    float* bufB   = (float*)ws;

    const int NB_EDGE = (N_EDGES + 255) / 256;

    // ---- CSR build + normalization ----
    hipMemsetAsync(cnt, 0, (size_t)N_NODES * 4, stream);
    k_count<<<NB_EDGE, 256, 0, stream>>>(ei, cnt);
    k_scan1<<<NBLK_NODE, 256, 0, stream>>>(cnt, rs, bsum);
    k_scan2<<<1, 256, 0, stream>>>(bsum, boff);
    k_scan3<<<NBLK_NODE, 256, 0, stream>>>(cnt, rs, boff, cursor, dinv);
    k_fill<<<NB_EDGE, 256, 0, stream>>>(ei, dinv, cursor, csr);

    // ---- layer 1 ----
    k_mm<N_FEAT><<<N_NODES / 16, 256, 0, stream>>>(x, W1, bufA);
    k_gather<<<N_NODES / 4, 256, 0, stream>>>(bufA, csr, rs, dinv, b1, bufB);

    // ---- layer 2 ----
    k_mm<HIDDEN><<<N_NODES / 16, 256, 0, stream>>>(bufB, W2, bufA);
    k_gather<<<N_NODES / 4, 256, 0, stream>>>(bufA, csr, rs, dinv, b2, bufB);

    // ---- output layer + softmax ----
    k_out<<<N_NODES / 16, 256, 0, stream>>>(bufB, Wout, bout, out);
}

// Round 4
// 275.041 us; speedup vs baseline: 2.3185x; 1.1853x over previous
//
#include <hip/hip_runtime.h>

#define N_NODES 50000
#define N_EDGES 800000
#define N_FEAT 128
#define HIDDEN 64
#define N_CLASSES 16
#define NBLK_NODE 196  // ceil(50000/256)

// cnt[dst]++ for every edge (int atomics; deg = cnt + 1 self-loop)
__global__ void k_count(const int* __restrict__ ei, int* __restrict__ cnt) {
    int e = blockIdx.x * 256 + threadIdx.x;
    if (e < N_EDGES) atomicAdd(&cnt[ei[N_EDGES + e]], 1);
}

// per-256-chunk exclusive scan of cnt -> rs (local), chunk totals -> bsum
__global__ void k_scan1(const int* __restrict__ cnt, int* __restrict__ rs,
                        int* __restrict__ bsum) {
    __shared__ int sm[256];
    int tid = threadIdx.x;
    int i = blockIdx.x * 256 + tid;
    int v = (i < N_NODES) ? cnt[i] : 0;
    sm[tid] = v;
    __syncthreads();
#pragma unroll
    for (int off = 1; off < 256; off <<= 1) {
        int t = (tid >= off) ? sm[tid - off] : 0;
        __syncthreads();
        sm[tid] += t;
        __syncthreads();
    }
    if (i < N_NODES) rs[i] = sm[tid] - v;  // exclusive
    if (tid == 255) bsum[blockIdx.x] = sm[255];
}

// single-block exclusive scan of the 196 chunk totals -> boff
__global__ void k_scan2(const int* __restrict__ bsum, int* __restrict__ boff) {
    __shared__ int sm[256];
    int tid = threadIdx.x;
    int v = (tid < NBLK_NODE) ? bsum[tid] : 0;
    sm[tid] = v;
    __syncthreads();
#pragma unroll
    for (int off = 1; off < 256; off <<= 1) {
        int t = (tid >= off) ? sm[tid - off] : 0;
        __syncthreads();
        sm[tid] += t;
        __syncthreads();
    }
    boff[tid] = sm[tid] - v;  // exclusive
}

// finalize: rs global offsets, cursor copy, dinv = (deg)^-1/2, sentinel rs[N]=E
__global__ void k_scan3(const int* __restrict__ cnt, int* __restrict__ rs,
                        const int* __restrict__ boff, int* __restrict__ cursor,
                        float* __restrict__ dinv) {
    int i = blockIdx.x * 256 + threadIdx.x;
    if (i < N_NODES) {
        int r = rs[i] + boff[blockIdx.x];
        rs[i] = r;
        cursor[i] = r;
        dinv[i] = rsqrtf((float)cnt[i] + 1.0f);
    }
    if (i == 0) rs[N_NODES] = N_EDGES;
}

// scatter edges into CSR buckets: csr[p] = {src, norm}
__global__ void k_fill(const int* __restrict__ ei, const float* __restrict__ dinv,
                       int* __restrict__ cursor, int2* __restrict__ csr) {
    int e = blockIdx.x * 256 + threadIdx.x;
    if (e >= N_EDGES) return;
    int s = ei[e];
    int d = ei[N_EDGES + e];
    float nrm = dinv[s] * dinv[d];
    int p = atomicAdd(&cursor[d], 1);
    csr[p] = make_int2(s, __float_as_int(nrm));
}

// LDS-tiled register-blocked GEMM: out[64 nodes x 64 feats] per block.
// A staged transposed (At[k][node], stride 68: keeps b128 alignment, 2-way
// banks on the transpose write = free). Thread = 4 nodes x 4 feats.
template <int K>
__global__ __launch_bounds__(256) void k_mm(const float* __restrict__ a,
                                            const float* __restrict__ w,
                                            float* __restrict__ out) {
    __shared__ __align__(16) float At[K * 68];
    __shared__ __align__(16) float Ws[K * HIDDEN];
    int tid = threadIdx.x;
    long nbase = (long)blockIdx.x * 64;

    // stage W (coalesced float4)
    for (int i = tid; i < K * 16; i += 256)
        *(float4*)&Ws[i * 4] = *(const float4*)&w[i * 4];
    // stage A transposed (coalesced float4 read, 4x b32 LDS writes)
    for (int i = tid; i < K * 16; i += 256) {
        int node = (i * 4) / K;
        int k = (i * 4) % K;
        long gn = nbase + node;
        float4 v = (gn < N_NODES) ? *(const float4*)&a[gn * K + k]
                                  : make_float4(0.f, 0.f, 0.f, 0.f);
        At[(k + 0) * 68 + node] = v.x;
        At[(k + 1) * 68 + node] = v.y;
        At[(k + 2) * 68 + node] = v.z;
        At[(k + 3) * 68 + node] = v.w;
    }
    __syncthreads();

    int tx = tid & 15;   // feature group: f = tx*4 .. tx*4+3
    int ty = tid >> 4;   // node group:    n = ty*4 .. ty*4+3
    float acc[4][4] = {};
#pragma unroll 8
    for (int k = 0; k < K; ++k) {
        float av[4], wv[4];
        *(float4*)av = *(const float4*)&At[k * 68 + ty * 4];
        *(float4*)wv = *(const float4*)&Ws[k * HIDDEN + tx * 4];
#pragma unroll
        for (int i = 0; i < 4; ++i)
#pragma unroll
            for (int j = 0; j < 4; ++j)
                acc[i][j] = fmaf(av[i], wv[j], acc[i][j]);
    }
#pragma unroll
    for (int i = 0; i < 4; ++i) {
        long n = nbase + ty * 4 + i;
        if (n < N_NODES) *(float4*)&out[n * HIDDEN + tx * 4] = *(float4*)acc[i];
    }
}

// fused aggregation: out[d,f] = relu( sum_{e->d} h[src,f]*norm + h[d,f]*dinv[d]^2 + b[f] )
// one wave per node, lane = feature. node forced scalar -> rs/csr via s_loads.
// 16-deep edge batches keep 16 independent h-row loads in flight.
__global__ void k_gather(const float* __restrict__ h, const int2* __restrict__ csr,
                         const int* __restrict__ rs, const float* __restrict__ dinv,
                         const float* __restrict__ bias, float* __restrict__ out) {
    int t = blockIdx.x * 256 + threadIdx.x;
    int node = __builtin_amdgcn_readfirstlane(t >> 6);  // wave-uniform
    int f = t & 63;
    int r0 = rs[node];
    int r1 = rs[node + 1];
    float di = dinv[node];
    float acc = h[(long)node * HIDDEN + f] * di * di;

    int j = r0;
    while (j + 16 <= r1) {
        int2 e[16];
        float v[16];
#pragma unroll
        for (int u = 0; u < 16; ++u) e[u] = csr[j + u];
#pragma unroll
        for (int u = 0; u < 16; ++u) v[u] = h[(long)e[u].x * HIDDEN + f];
#pragma unroll
        for (int u = 0; u < 16; ++u) acc = fmaf(v[u], __int_as_float(e[u].y), acc);
        j += 16;
    }
    while (j + 4 <= r1) {
        int2 e0 = csr[j], e1 = csr[j + 1], e2 = csr[j + 2], e3 = csr[j + 3];
        float v0 = h[(long)e0.x * HIDDEN + f];
        float v1 = h[(long)e1.x * HIDDEN + f];
        float v2 = h[(long)e2.x * HIDDEN + f];
        float v3 = h[(long)e3.x * HIDDEN + f];
        acc = fmaf(v0, __int_as_float(e0.y), acc);
        acc = fmaf(v1, __int_as_float(e1.y), acc);
        acc = fmaf(v2, __int_as_float(e2.y), acc);
        acc = fmaf(v3, __int_as_float(e3.y), acc);
        j += 4;
    }
    while (j < r1) {
        int2 e0 = csr[j];
        acc = fmaf(h[(long)e0.x * HIDDEN + f], __int_as_float(e0.y), acc);
        ++j;
    }
    out[(long)node * HIDDEN + f] = fmaxf(acc + bias[f], 0.0f);
}

// logits = h @ Wout + bout, softmax over 16 classes (16 lanes per node).
__global__ void k_out(const float* __restrict__ h, const float* __restrict__ w,
                      const float* __restrict__ b, float* __restrict__ out) {
    __shared__ float Ws[HIDDEN * N_CLASSES];
    __shared__ float bs[N_CLASSES];
    int tid = threadIdx.x;
    for (int i = tid; i < HIDDEN * N_CLASSES; i += 256) Ws[i] = w[i];
    if (tid < N_CLASSES) bs[tid] = b[tid];
    __syncthreads();
    int node = blockIdx.x * 16 + (tid >> 4);
    int c = tid & 15;
    const float* hr = h + (long)node * HIDDEN;
    float acc = bs[c];
#pragma unroll
    for (int k = 0; k < HIDDEN; ++k) acc = fmaf(hr[k], Ws[k * N_CLASSES + c], acc);
    float m = acc;
#pragma unroll
    for (int off = 8; off; off >>= 1) m = fmaxf(m, __shfl_xor(m, off, 16));
    float ex = expf(acc - m);
    float s = ex;
#pragma unroll
    for (int off = 8; off; off >>= 1) s += __shfl_xor(s, off, 16);
    out[(long)node * N_CLASSES + c] = ex / s;
}

extern "C" void kernel_launch(void* const* d_in, const int* in_sizes, int n_in,
                              void* d_out, int out_size, void* d_ws, size_t ws_size,
                              hipStream_t stream) {
    const float* x    = (const float*)d_in[0];
    const int*   ei   = (const int*)d_in[1];
    const float* W1   = (const float*)d_in[2];
    const float* b1   = (const float*)d_in[3];
    const float* W2   = (const float*)d_in[4];
    const float* b2   = (const float*)d_in[5];
    const float* Wout = (const float*)d_in[6];
    const float* bout = (const float*)d_in[7];
    float* out = (float*)d_out;

    char* ws = (char*)d_ws;
    const size_t SZ_NODE_I = 200192;  // 50000*4 rounded to 256
    int*   cnt    = (int*)ws;                          ws += SZ_NODE_I;
    int*   rs     = (int*)ws;                          ws += SZ_NODE_I + 256;  // 50001 ints
    int*   cursor = (int*)ws;                          ws += SZ_NODE_I;
    float* dinv   = (float*)ws;                        ws += SZ_NODE_I;
    int*   bsum   = (int*)ws;                          ws += 1024;
    int*   boff   = (int*)ws;                          ws += 1024;
    int2*  csr    = (int2*)ws;                         ws += (size_t)N_EDGES * 8;
    float* bufA   = (float*)ws;                        ws += (size_t)N_NODES * HIDDEN * 4;
    float* bufB   = (float*)ws;

    const int NB_EDGE = (N_EDGES + 255) / 256;
    const int NB_MM = (N_NODES + 63) / 64;  // 782

    // ---- CSR build + normalization ----
    hipMemsetAsync(cnt, 0, (size_t)N_NODES * 4, stream);
    k_count<<<NB_EDGE, 256, 0, stream>>>(ei, cnt);
    k_scan1<<<NBLK_NODE, 256, 0, stream>>>(cnt, rs, bsum);
    k_scan2<<<1, 256, 0, stream>>>(bsum, boff);
    k_scan3<<<NBLK_NODE, 256, 0, stream>>>(cnt, rs, boff, cursor, dinv);
    k_fill<<<NB_EDGE, 256, 0, stream>>>(ei, dinv, cursor, csr);

    // ---- layer 1 ----
    k_mm<N_FEAT><<<NB_MM, 256, 0, stream>>>(x, W1, bufA);
    k_gather<<<N_NODES / 4, 256, 0, stream>>>(bufA, csr, rs, dinv, b1, bufB);

    // ---- layer 2 ----
    k_mm<HIDDEN><<<NB_MM, 256, 0, stream>>>(bufB, W2, bufA);
    k_gather<<<N_NODES / 4, 256, 0, stream>>>(bufA, csr, rs, dinv, b2, bufB);

    // ---- output layer + softmax ----
    k_out<<<N_NODES / 16, 256, 0, stream>>>(bufB, Wout, bout, out);
}

// Round 5
// 258.286 us; speedup vs baseline: 2.4689x; 1.0649x over previous
//
#include <hip/hip_runtime.h>

#define N_NODES 50000
#define N_EDGES 800000
#define N_FEAT 128
#define HIDDEN 64
#define N_CLASSES 16
#define NBLK_NODE 196   // ceil(50000/256); also number of 256-node dst tiles
#define FS_CAP 4864     // fine-sort staging capacity (recs); tile mean 4096, +12 sigma

// cnt[dst]++ for every edge (int atomics; deg = cnt + 1 self-loop)
__global__ void k_count(const int* __restrict__ ei, int* __restrict__ cnt) {
    int e = blockIdx.x * 256 + threadIdx.x;
    if (e < N_EDGES) atomicAdd(&cnt[ei[N_EDGES + e]], 1);
}

// per-256-chunk exclusive scan of cnt -> rs (local), chunk totals -> bsum
__global__ void k_scan1(const int* __restrict__ cnt, int* __restrict__ rs,
                        int* __restrict__ bsum) {
    __shared__ int sm[256];
    int tid = threadIdx.x;
    int i = blockIdx.x * 256 + tid;
    int v = (i < N_NODES) ? cnt[i] : 0;
    sm[tid] = v;
    __syncthreads();
#pragma unroll
    for (int off = 1; off < 256; off <<= 1) {
        int t = (tid >= off) ? sm[tid - off] : 0;
        __syncthreads();
        sm[tid] += t;
        __syncthreads();
    }
    if (i < N_NODES) rs[i] = sm[tid] - v;  // exclusive
    if (tid == 255) bsum[blockIdx.x] = sm[255];
}

// single-block exclusive scan of the 196 chunk totals -> boff
__global__ void k_scan2(const int* __restrict__ bsum, int* __restrict__ boff) {
    __shared__ int sm[256];
    int tid = threadIdx.x;
    int v = (tid < NBLK_NODE) ? bsum[tid] : 0;
    sm[tid] = v;
    __syncthreads();
#pragma unroll
    for (int off = 1; off < 256; off <<= 1) {
        int t = (tid >= off) ? sm[tid - off] : 0;
        __syncthreads();
        sm[tid] += t;
        __syncthreads();
    }
    boff[tid] = sm[tid] - v;  // exclusive
}

// finalize: rs global offsets, tile cursors (= rs[t*256]), dinv, rs tail padding
__global__ void k_scan3(const int* __restrict__ cnt, int* __restrict__ rs,
                        const int* __restrict__ boff, int* __restrict__ tileCursor,
                        float* __restrict__ dinv) {
    int i = blockIdx.x * 256 + threadIdx.x;
    if (i < N_NODES) {
        int r = rs[i] + boff[blockIdx.x];
        rs[i] = r;
        dinv[i] = rsqrtf((float)cnt[i] + 1.0f);
        if ((i & 255) == 0) tileCursor[i >> 8] = r;
    } else {
        rs[i] = N_EDGES;  // pad 50000..50175 for fine-sort of the last tile
    }
    if (i == 0) rs[NBLK_NODE * 256] = N_EDGES;  // rs[50176]
}

// coarse partition into 196 dst-tiles. Per block: LDS histogram, one global
// atomic per (block,tile) reserves a contiguous run -> runs are block-owned,
// so the 8B record stores merge in that XCD's L2 (kills write amplification).
// record: { src | dstLocal<<16 , norm }   (src < 65536, dstLocal < 256)
__global__ __launch_bounds__(256) void k_part(const int* __restrict__ ei,
                                              const float* __restrict__ dinv,
                                              int* __restrict__ tileCursor,
                                              int2* __restrict__ binned) {
    __shared__ int cnt[NBLK_NODE], base[NBLK_NODE], cur[NBLK_NODE];
    int tid = threadIdx.x;
    int start = blockIdx.x * 4096;
    if (tid < NBLK_NODE) cnt[tid] = 0;
    __syncthreads();
    int s[16], d[16];
#pragma unroll
    for (int u = 0; u < 16; ++u) {
        int e = start + u * 256 + tid;
        if (e < N_EDGES) {
            s[u] = ei[e];
            d[u] = ei[N_EDGES + e];
            atomicAdd(&cnt[d[u] >> 8], 1);
        } else {
            s[u] = -1;
            d[u] = 0;
        }
    }
    __syncthreads();
    if (tid < NBLK_NODE) {
        base[tid] = atomicAdd(&tileCursor[tid], cnt[tid]);
        cur[tid] = 0;
    }
    __syncthreads();
    float nm[16];
#pragma unroll
    for (int u = 0; u < 16; ++u)
        if (s[u] >= 0) nm[u] = dinv[s[u]] * dinv[d[u]];
#pragma unroll
    for (int u = 0; u < 16; ++u) {
        if (s[u] < 0) continue;
        int t = d[u] >> 8;
        int r = atomicAdd(&cur[t], 1);
        binned[base[t] + r] = make_int2(s[u] | ((d[u] & 255) << 16), __float_as_int(nm[u]));
    }
}

// fine counting-sort within a tile: read the tile's contiguous run (coalesced),
// rank by node via LDS atomics, stage in LDS, write node-ordered CSR coalesced.
// Fallback to direct global scatter if a tile overflows staging (p ~ 0).
__global__ __launch_bounds__(256) void k_finesort(const int2* __restrict__ binned,
                                                  const int* __restrict__ rs,
                                                  int2* __restrict__ csr) {
    __shared__ int2 staging[FS_CAP];
    __shared__ int rsT[257];
    __shared__ int cur[256];
    int tid = threadIdx.x;
    int n0 = blockIdx.x * 256;
    for (int k = tid; k < 257; k += 256) rsT[k] = rs[n0 + k];
    cur[tid] = 0;
    __syncthreads();
    int beg = rsT[0];
    int m = rsT[256] - beg;
    bool staged = (m <= FS_CAP);
    for (int i = tid; i < m; i += 256) {
        int2 rec = binned[beg + i];
        int dl = (rec.x >> 16) & 255;
        int r = atomicAdd(&cur[dl], 1);
        int2 o = make_int2(rec.x & 0xFFFF, rec.y);
        if (staged) staging[rsT[dl] - beg + r] = o;
        else csr[rsT[dl] + r] = o;
    }
    __syncthreads();
    if (staged)
        for (int i = tid; i < m; i += 256) csr[beg + i] = staging[i];
}

// LDS-tiled register-blocked GEMM: out[64 nodes x 64 feats] per block.
// A staged transposed (At[k][node], stride 68). Thread = 4 nodes x 4 feats.
template <int K>
__global__ __launch_bounds__(256) void k_mm(const float* __restrict__ a,
                                            const float* __restrict__ w,
                                            float* __restrict__ out) {
    __shared__ __align__(16) float At[K * 68];
    __shared__ __align__(16) float Ws[K * HIDDEN];
    int tid = threadIdx.x;
    long nbase = (long)blockIdx.x * 64;

    for (int i = tid; i < K * 16; i += 256)
        *(float4*)&Ws[i * 4] = *(const float4*)&w[i * 4];
    for (int i = tid; i < K * 16; i += 256) {
        int node = (i * 4) / K;
        int k = (i * 4) % K;
        long gn = nbase + node;
        float4 v = (gn < N_NODES) ? *(const float4*)&a[gn * K + k]
                                  : make_float4(0.f, 0.f, 0.f, 0.f);
        At[(k + 0) * 68 + node] = v.x;
        At[(k + 1) * 68 + node] = v.y;
        At[(k + 2) * 68 + node] = v.z;
        At[(k + 3) * 68 + node] = v.w;
    }
    __syncthreads();

    int tx = tid & 15;
    int ty = tid >> 4;
    float acc[4][4] = {};
#pragma unroll 8
    for (int k = 0; k < K; ++k) {
        float av[4], wv[4];
        *(float4*)av = *(const float4*)&At[k * 68 + ty * 4];
        *(float4*)wv = *(const float4*)&Ws[k * HIDDEN + tx * 4];
#pragma unroll
        for (int i = 0; i < 4; ++i)
#pragma unroll
            for (int j = 0; j < 4; ++j)
                acc[i][j] = fmaf(av[i], wv[j], acc[i][j]);
    }
#pragma unroll
    for (int i = 0; i < 4; ++i) {
        long n = nbase + ty * 4 + i;
        if (n < N_NODES) *(float4*)&out[n * HIDDEN + tx * 4] = *(float4*)acc[i];
    }
}

// fused aggregation: out[d,f] = relu( sum_{e->d} h[src,f]*norm + h[d,f]*dinv[d]^2 + b[f] )
// one wave per node, lane = feature; 16-deep independent edge batches.
__global__ void k_gather(const float* __restrict__ h, const int2* __restrict__ csr,
                         const int* __restrict__ rs, const float* __restrict__ dinv,
                         const float* __restrict__ bias, float* __restrict__ out) {
    int t = blockIdx.x * 256 + threadIdx.x;
    int node = __builtin_amdgcn_readfirstlane(t >> 6);  // wave-uniform
    int f = t & 63;
    int r0 = rs[node];
    int r1 = rs[node + 1];
    float di = dinv[node];
    float acc = h[(long)node * HIDDEN + f] * di * di;

    int j = r0;
    while (j + 16 <= r1) {
        int2 e[16];
        float v[16];
#pragma unroll
        for (int u = 0; u < 16; ++u) e[u] = csr[j + u];
#pragma unroll
        for (int u = 0; u < 16; ++u) v[u] = h[(long)e[u].x * HIDDEN + f];
#pragma unroll
        for (int u = 0; u < 16; ++u) acc = fmaf(v[u], __int_as_float(e[u].y), acc);
        j += 16;
    }
    while (j + 4 <= r1) {
        int2 e0 = csr[j], e1 = csr[j + 1], e2 = csr[j + 2], e3 = csr[j + 3];
        float v0 = h[(long)e0.x * HIDDEN + f];
        float v1 = h[(long)e1.x * HIDDEN + f];
        float v2 = h[(long)e2.x * HIDDEN + f];
        float v3 = h[(long)e3.x * HIDDEN + f];
        acc = fmaf(v0, __int_as_float(e0.y), acc);
        acc = fmaf(v1, __int_as_float(e1.y), acc);
        acc = fmaf(v2, __int_as_float(e2.y), acc);
        acc = fmaf(v3, __int_as_float(e3.y), acc);
        j += 4;
    }
    while (j < r1) {
        int2 e0 = csr[j];
        acc = fmaf(h[(long)e0.x * HIDDEN + f], __int_as_float(e0.y), acc);
        ++j;
    }
    out[(long)node * HIDDEN + f] = fmaxf(acc + bias[f], 0.0f);
}

// logits = h @ Wout + bout, softmax over 16 classes (16 lanes per node).
__global__ void k_out(const float* __restrict__ h, const float* __restrict__ w,
                      const float* __restrict__ b, float* __restrict__ out) {
    __shared__ float Ws[HIDDEN * N_CLASSES];
    __shared__ float bs[N_CLASSES];
    int tid = threadIdx.x;
    for (int i = tid; i < HIDDEN * N_CLASSES; i += 256) Ws[i] = w[i];
    if (tid < N_CLASSES) bs[tid] = b[tid];
    __syncthreads();
    int node = blockIdx.x * 16 + (tid >> 4);
    int c = tid & 15;
    const float* hr = h + (long)node * HIDDEN;
    float acc = bs[c];
#pragma unroll
    for (int k = 0; k < HIDDEN; ++k) acc = fmaf(hr[k], Ws[k * N_CLASSES + c], acc);
    float m = acc;
#pragma unroll
    for (int off = 8; off; off >>= 1) m = fmaxf(m, __shfl_xor(m, off, 16));
    float ex = expf(acc - m);
    float s = ex;
#pragma unroll
    for (int off = 8; off; off >>= 1) s += __shfl_xor(s, off, 16);
    out[(long)node * N_CLASSES + c] = ex / s;
}

extern "C" void kernel_launch(void* const* d_in, const int* in_sizes, int n_in,
                              void* d_out, int out_size, void* d_ws, size_t ws_size,
                              hipStream_t stream) {
    const float* x    = (const float*)d_in[0];
    const int*   ei   = (const int*)d_in[1];
    const float* W1   = (const float*)d_in[2];
    const float* b1   = (const float*)d_in[3];
    const float* W2   = (const float*)d_in[4];
    const float* b2   = (const float*)d_in[5];
    const float* Wout = (const float*)d_in[6];
    const float* bout = (const float*)d_in[7];
    float* out = (float*)d_out;

    char* ws = (char*)d_ws;
    const size_t SZ_NODE_I = 200192;  // 50000*4 rounded up
    int*   cnt     = (int*)ws;                         ws += SZ_NODE_I;
    int*   rs      = (int*)ws;                         ws += 202240;  // 50433 ints (incl. pad to 50176+1)
    float* dinv    = (float*)ws;                       ws += SZ_NODE_I;
    int*   bsum    = (int*)ws;                         ws += 1024;
    int*   boff    = (int*)ws;                         ws += 1024;
    int*   tileCur = (int*)ws;                         ws += 1024;
    int2*  csr     = (int2*)ws;                        ws += (size_t)N_EDGES * 8;
    float* bufA    = (float*)ws;                       ws += (size_t)N_NODES * HIDDEN * 4;
    float* bufB    = (float*)ws;
    int2*  binned  = (int2*)bufA;  // binned (6.4 MB) dies before mm128 writes bufA

    const int NB_EDGE = (N_EDGES + 255) / 256;
    const int NB_MM = (N_NODES + 63) / 64;     // 782
    const int NB_PART = (N_EDGES + 4095) / 4096;  // 196

    // ---- degree count + CSR offsets + dinv + tile cursors ----
    hipMemsetAsync(cnt, 0, (size_t)N_NODES * 4, stream);
    k_count<<<NB_EDGE, 256, 0, stream>>>(ei, cnt);
    k_scan1<<<NBLK_NODE, 256, 0, stream>>>(cnt, rs, bsum);
    k_scan2<<<1, 256, 0, stream>>>(bsum, boff);
    k_scan3<<<NBLK_NODE, 256, 0, stream>>>(cnt, rs, boff, tileCur, dinv);

    // ---- two-phase edge sort (replaces atomic-cursor k_fill) ----
    k_part<<<NB_PART, 256, 0, stream>>>(ei, dinv, tileCur, binned);
    k_finesort<<<NBLK_NODE, 256, 0, stream>>>(binned, rs, csr);

    // ---- layer 1 ----
    k_mm<N_FEAT><<<NB_MM, 256, 0, stream>>>(x, W1, bufA);
    k_gather<<<N_NODES / 4, 256, 0, stream>>>(bufA, csr, rs, dinv, b1, bufB);

    // ---- layer 2 ----
    k_mm<HIDDEN><<<NB_MM, 256, 0, stream>>>(bufB, W2, bufA);
    k_gather<<<N_NODES / 4, 256, 0, stream>>>(bufA, csr, rs, dinv, b2, bufB);

    // ---- output layer + softmax ----
    k_out<<<N_NODES / 16, 256, 0, stream>>>(bufB, Wout, bout, out);
}

// Round 6
// 217.826 us; speedup vs baseline: 2.9274x; 1.1857x over previous
//
#include <hip/hip_runtime.h>
#include <hip/hip_fp16.h>

#define N_NODES 50000
#define N_EDGES 800000
#define N_FEAT 128
#define HIDDEN 64
#define N_CLASSES 16
#define NBLK_NODE 196   // number of 256-node dst tiles (ceil(50000/256))
#define FS_CAP 8192     // fine-sort staging capacity (recs); tile mean 4083, sigma ~64

// ---- phase 1: per-tile edge histogram (LDS-staged; 196 global atomics/block) ----
__global__ __launch_bounds__(256) void k_tilecount(const int* __restrict__ ei,
                                                   int* __restrict__ tileCnt) {
    __shared__ int c[NBLK_NODE];
    int tid = threadIdx.x;
    if (tid < NBLK_NODE) c[tid] = 0;
    __syncthreads();
    int start = blockIdx.x * 4096;
#pragma unroll
    for (int u = 0; u < 16; ++u) {
        int e = start + u * 256 + tid;
        if (e < N_EDGES) atomicAdd(&c[ei[N_EDGES + e] >> 8], 1);
    }
    __syncthreads();
    if (tid < NBLK_NODE && c[tid]) atomicAdd(&tileCnt[tid], c[tid]);
}

// ---- phase 2: partition edges into 196 dst-tile runs. Tile bases come from an
// in-block scan of tileCnt; each block reserves a contiguous sub-run with ONE
// global atomic per (block,tile) -> block-owned 4B record stores merge in L2.
// record: src | dstLocal<<16   (src < 2^16, dstLocal < 256)
__global__ __launch_bounds__(256) void k_part(const int* __restrict__ ei,
                                              const int* __restrict__ tileCnt,
                                              int* __restrict__ tileCur,
                                              int* __restrict__ binned) {
    __shared__ int sc[256];
    __shared__ int cnt[NBLK_NODE], gbase[NBLK_NODE], base[NBLK_NODE], cur[NBLK_NODE];
    int tid = threadIdx.x;
    int v = (tid < NBLK_NODE) ? tileCnt[tid] : 0;
    sc[tid] = v;
    __syncthreads();
#pragma unroll
    for (int off = 1; off < 256; off <<= 1) {
        int t = (tid >= off) ? sc[tid - off] : 0;
        __syncthreads();
        sc[tid] += t;
        __syncthreads();
    }
    if (tid < NBLK_NODE) { gbase[tid] = sc[tid] - v; cnt[tid] = 0; }
    __syncthreads();
    int start = blockIdx.x * 4096;
    int s[16], d[16];
#pragma unroll
    for (int u = 0; u < 16; ++u) {
        int e = start + u * 256 + tid;
        if (e < N_EDGES) {
            s[u] = ei[e];
            d[u] = ei[N_EDGES + e];
            atomicAdd(&cnt[d[u] >> 8], 1);
        } else s[u] = -1;
    }
    __syncthreads();
    if (tid < NBLK_NODE) {
        base[tid] = gbase[tid] + atomicAdd(&tileCur[tid], cnt[tid]);
        cur[tid] = 0;
    }
    __syncthreads();
#pragma unroll
    for (int u = 0; u < 16; ++u) {
        if (s[u] < 0) continue;
        int t = d[u] >> 8;
        int r = atomicAdd(&cur[t], 1);
        binned[base[t] + r] = s[u] | ((d[u] & 255) << 16);
    }
}

// ---- phase 3: per-tile counting sort. Also derives degree -> dinv and the
// per-node CSR offsets rs (so no separate count/scan kernels are needed).
__global__ __launch_bounds__(256) void k_finesort(const int* __restrict__ binned,
                                                  const int* __restrict__ tileCnt,
                                                  int* __restrict__ csr,
                                                  int* __restrict__ rs,
                                                  float* __restrict__ dinv) {
    __shared__ int stage[FS_CAP];
    __shared__ int sc[256];
    __shared__ int cnt256[256];
    __shared__ int nodeOff[257];
    int tid = threadIdx.x;
    int tb = blockIdx.x;
    // tile-level inclusive scan -> run boundaries
    int v = (tid < NBLK_NODE) ? tileCnt[tid] : 0;
    sc[tid] = v;
    __syncthreads();
#pragma unroll
    for (int off = 1; off < 256; off <<= 1) {
        int t = (tid >= off) ? sc[tid - off] : 0;
        __syncthreads();
        sc[tid] += t;
        __syncthreads();
    }
    int beg = (tb == 0) ? 0 : sc[tb - 1];
    int m = sc[tb] - beg;
    cnt256[tid] = 0;
    __syncthreads();
    // per-node counts
    for (int i = tid; i < m; i += 256)
        atomicAdd(&cnt256[(binned[beg + i] >> 16) & 255], 1);
    __syncthreads();
    int myc = cnt256[tid];
    dinv[tb * 256 + tid] = rsqrtf((float)myc + 1.0f);  // deg = in-edges + self-loop
    // node-level scan -> rs + local offsets
    sc[tid] = myc;
    __syncthreads();
#pragma unroll
    for (int off = 1; off < 256; off <<= 1) {
        int t = (tid >= off) ? sc[tid - off] : 0;
        __syncthreads();
        sc[tid] += t;
        __syncthreads();
    }
    nodeOff[tid] = sc[tid] - myc;
    rs[tb * 256 + tid] = beg + sc[tid] - myc;
    if (tid == 255) {
        nodeOff[256] = sc[255];
        rs[tb * 256 + 256] = beg + sc[255];  // next tile writes same value: benign
    }
    cnt256[tid] = 0;
    __syncthreads();
    bool staged = (m <= FS_CAP);
    for (int i = tid; i < m; i += 256) {
        int rec = binned[beg + i];
        int dl = (rec >> 16) & 255;
        int r = atomicAdd(&cnt256[dl], 1);
        int src = rec & 0xFFFF;
        if (staged) stage[nodeOff[dl] + r] = src;
        else csr[beg + nodeOff[dl] + r] = src;  // overflow fallback (p ~ 0)
    }
    __syncthreads();
    if (staged)
        for (int i = tid; i < m; i += 256) csr[beg + i] = stage[i];
}

// ---- LDS-tiled register-blocked GEMM, fp32 accumulate, fp16 output ----
// out[64 nodes x 64 feats]/block; At[k][node] stride 68; thread = 4x4 tile.
template <int K, typename TIn>
__global__ __launch_bounds__(256) void k_mm(const TIn* __restrict__ a,
                                            const float* __restrict__ w,
                                            __half* __restrict__ out) {
    __shared__ __align__(16) float At[K * 68];
    __shared__ __align__(16) float Ws[K * HIDDEN];
    int tid = threadIdx.x;
    long nbase = (long)blockIdx.x * 64;

    for (int i = tid; i < K * 16; i += 256)
        *(float4*)&Ws[i * 4] = *(const float4*)&w[i * 4];
    for (int i = tid; i < K * 16; i += 256) {
        int node = (i * 4) / K;
        int k = (i * 4) % K;
        long gn = nbase + node;
        float4 v;
        if (gn < N_NODES) {
            if constexpr (sizeof(TIn) == 2) {
                __half2 p0 = *(const __half2*)&a[gn * K + k];
                __half2 p1 = *(const __half2*)&a[gn * K + k + 2];
                float2 f0 = __half22float2(p0), f1 = __half22float2(p1);
                v = make_float4(f0.x, f0.y, f1.x, f1.y);
            } else {
                v = *(const float4*)&a[gn * K + k];
            }
        } else v = make_float4(0.f, 0.f, 0.f, 0.f);
        At[(k + 0) * 68 + node] = v.x;
        At[(k + 1) * 68 + node] = v.y;
        At[(k + 2) * 68 + node] = v.z;
        At[(k + 3) * 68 + node] = v.w;
    }
    __syncthreads();

    int tx = tid & 15;
    int ty = tid >> 4;
    float acc[4][4] = {};
#pragma unroll 8
    for (int k = 0; k < K; ++k) {
        float av[4], wv[4];
        *(float4*)av = *(const float4*)&At[k * 68 + ty * 4];
        *(float4*)wv = *(const float4*)&Ws[k * HIDDEN + tx * 4];
#pragma unroll
        for (int i = 0; i < 4; ++i)
#pragma unroll
            for (int j = 0; j < 4; ++j)
                acc[i][j] = fmaf(av[i], wv[j], acc[i][j]);
    }
#pragma unroll
    for (int i = 0; i < 4; ++i) {
        long n = nbase + ty * 4 + i;
        if (n < N_NODES) {
            __half2* op = (__half2*)&out[n * HIDDEN + tx * 4];
            op[0] = __floats2half2_rn(acc[i][0], acc[i][1]);
            op[1] = __floats2half2_rn(acc[i][2], acc[i][3]);
        }
    }
}

// ---- fused aggregation, fp16 rows, norm computed on the fly ----
// out[d,f] = relu( sum_e h[src,f]*dinv[s]*dinv[d] + h[d,f]*dinv[d]^2 + b[f] )
__global__ void k_gather(const __half* __restrict__ h, const int* __restrict__ csr,
                         const int* __restrict__ rs, const float* __restrict__ dinv,
                         const float* __restrict__ bias, __half* __restrict__ out) {
    int t = blockIdx.x * 256 + threadIdx.x;
    int node = __builtin_amdgcn_readfirstlane(t >> 6);  // wave-uniform
    int f = t & 63;
    int r0 = rs[node];
    int r1 = rs[node + 1];
    float dd = dinv[node];
    float acc = __half2float(h[(long)node * HIDDEN + f]) * dd * dd;

    int j = r0;
    while (j + 16 <= r1) {
        int s[16];
        float w[16], v[16];
#pragma unroll
        for (int u = 0; u < 16; ++u) s[u] = csr[j + u];
#pragma unroll
        for (int u = 0; u < 16; ++u) w[u] = dinv[s[u]];
#pragma unroll
        for (int u = 0; u < 16; ++u) v[u] = __half2float(h[(long)s[u] * HIDDEN + f]);
#pragma unroll
        for (int u = 0; u < 16; ++u) acc = fmaf(v[u], w[u] * dd, acc);
        j += 16;
    }
    while (j + 4 <= r1) {
        int s0 = csr[j], s1 = csr[j + 1], s2 = csr[j + 2], s3 = csr[j + 3];
        float w0 = dinv[s0], w1 = dinv[s1], w2 = dinv[s2], w3 = dinv[s3];
        float v0 = __half2float(h[(long)s0 * HIDDEN + f]);
        float v1 = __half2float(h[(long)s1 * HIDDEN + f]);
        float v2 = __half2float(h[(long)s2 * HIDDEN + f]);
        float v3 = __half2float(h[(long)s3 * HIDDEN + f]);
        acc = fmaf(v0, w0 * dd, acc);
        acc = fmaf(v1, w1 * dd, acc);
        acc = fmaf(v2, w2 * dd, acc);
        acc = fmaf(v3, w3 * dd, acc);
        j += 4;
    }
    while (j < r1) {
        int s0 = csr[j];
        acc = fmaf(__half2float(h[(long)s0 * HIDDEN + f]), dinv[s0] * dd, acc);
        ++j;
    }
    out[(long)node * HIDDEN + f] = __float2half(fmaxf(acc + bias[f], 0.0f));
}

// ---- logits = h @ Wout + bout, softmax over 16 classes (fp32 math) ----
__global__ void k_out(const __half* __restrict__ h, const float* __restrict__ w,
                      const float* __restrict__ b, float* __restrict__ out) {
    __shared__ float Ws[HIDDEN * N_CLASSES];
    __shared__ float bs[N_CLASSES];
    int tid = threadIdx.x;
    for (int i = tid; i < HIDDEN * N_CLASSES; i += 256) Ws[i] = w[i];
    if (tid < N_CLASSES) bs[tid] = b[tid];
    __syncthreads();
    int node = blockIdx.x * 16 + (tid >> 4);
    int c = tid & 15;
    const __half* hr = h + (long)node * HIDDEN;
    float acc = bs[c];
#pragma unroll
    for (int k = 0; k < HIDDEN; ++k)
        acc = fmaf(__half2float(hr[k]), Ws[k * N_CLASSES + c], acc);
    float m = acc;
#pragma unroll
    for (int off = 8; off; off >>= 1) m = fmaxf(m, __shfl_xor(m, off, 16));
    float ex = expf(acc - m);
    float s = ex;
#pragma unroll
    for (int off = 8; off; off >>= 1) s += __shfl_xor(s, off, 16);
    out[(long)node * N_CLASSES + c] = ex / s;
}

extern "C" void kernel_launch(void* const* d_in, const int* in_sizes, int n_in,
                              void* d_out, int out_size, void* d_ws, size_t ws_size,
                              hipStream_t stream) {
    const float* x    = (const float*)d_in[0];
    const int*   ei   = (const int*)d_in[1];
    const float* W1   = (const float*)d_in[2];
    const float* b1   = (const float*)d_in[3];
    const float* W2   = (const float*)d_in[4];
    const float* b2   = (const float*)d_in[5];
    const float* Wout = (const float*)d_in[6];
    const float* bout = (const float*)d_in[7];
    float* out = (float*)d_out;

    char* ws = (char*)d_ws;
    int*    rs      = (int*)ws;                        ws += 202240;  // 50433 ints
    float*  dinv    = (float*)ws;                      ws += 200960;  // 50176 floats, padded
    int*    tiles   = (int*)ws;                        ws += 2048;    // tileCnt[256] + tileCur[256]
    int*    csr     = (int*)ws;                        ws += (size_t)N_EDGES * 4;
    __half* bufA    = (__half*)ws;                     ws += (size_t)N_NODES * HIDDEN * 2;
    __half* bufB    = (__half*)ws;
    int* tileCnt = tiles;
    int* tileCur = tiles + 256;
    int* binned  = (int*)bufA;  // 3.2 MB alias; dies before k_mm<128> writes bufA

    const int NB_MM = (N_NODES + 63) / 64;        // 782
    const int NB_E16 = (N_EDGES + 4095) / 4096;   // 196

    // ---- CSR build: tile histogram -> partition -> counting sort (+deg/dinv/rs) ----
    hipMemsetAsync(tiles, 0, 2048, stream);
    k_tilecount<<<NB_E16, 256, 0, stream>>>(ei, tileCnt);
    k_part<<<NB_E16, 256, 0, stream>>>(ei, tileCnt, tileCur, binned);
    k_finesort<<<NBLK_NODE, 256, 0, stream>>>(binned, tileCnt, csr, rs, dinv);

    // ---- layer 1 ----
    k_mm<N_FEAT, float><<<NB_MM, 256, 0, stream>>>(x, W1, bufA);
    k_gather<<<N_NODES / 4, 256, 0, stream>>>(bufA, csr, rs, dinv, b1, bufB);

    // ---- layer 2 ----
    k_mm<HIDDEN, __half><<<NB_MM, 256, 0, stream>>>(bufB, W2, bufA);
    k_gather<<<N_NODES / 4, 256, 0, stream>>>(bufA, csr, rs, dinv, b2, bufB);

    // ---- output layer + softmax ----
    k_out<<<N_NODES / 16, 256, 0, stream>>>(bufB, Wout, bout, out);
}